// Round 2
// baseline (19073.668 us; speedup 1.0000x reference)
//
#include <hip/hip_runtime.h>
#include <hip/hip_bf16.h>
#include <math.h>

// Problem constants
constexpr int T    = 16;
constexpr int NN   = 20000;
constexpr int E    = 320000;
constexpr int P    = 4096;
constexpr int DIN  = 128;
constexpr int H    = 256;
constexpr int NH   = 8;
constexpr int LAY  = 2;
constexpr int FF   = 2048;
constexpr int D    = 2 * H;       // 512
constexpr int HD   = D / NH;      // 64

// ---------------------------------------------------------------------------
// CSR build: histogram of dst
__global__ void k_count(const int* __restrict__ dst, int* __restrict__ counts) {
  int e = blockIdx.x * 256 + threadIdx.x;
  int t = blockIdx.y;
  if (e < E) atomicAdd(&counts[t * NN + dst[(size_t)t * E + e]], 1);
}

// exclusive scan of counts -> rowptr, one block per t
__global__ __launch_bounds__(1024) void k_scan(const int* __restrict__ counts,
                                               int* __restrict__ rowptr) {
  __shared__ int s[1024];
  int t = blockIdx.x, tid = threadIdx.x;
  int running = 0;
  for (int base = 0; base < NN; base += 1024) {
    int i = base + tid;
    int v = (i < NN) ? counts[t * NN + i] : 0;
    s[tid] = v;
    __syncthreads();
    for (int off = 1; off < 1024; off <<= 1) {
      int u = (tid >= off) ? s[tid - off] : 0;
      __syncthreads();
      s[tid] += u;
      __syncthreads();
    }
    if (i < NN) rowptr[t * (NN + 1) + i] = running + s[tid] - v;
    int tot = s[1023];
    __syncthreads();
    running += tot;
  }
  if (tid == 0) rowptr[t * (NN + 1) + NN] = running;
}

// scatter edge srcs into CSR slots
__global__ void k_scatter(const int* __restrict__ src, const int* __restrict__ dst,
                          const int* __restrict__ rowptr, int* __restrict__ cur,
                          int* __restrict__ csr) {
  int e = blockIdx.x * 256 + threadIdx.x;
  int t = blockIdx.y;
  if (e < E) {
    int dd = dst[(size_t)t * E + e];
    int pos = rowptr[t * (NN + 1) + dd] + atomicAdd(&cur[t * NN + dd], 1);
    csr[(size_t)t * E + pos] = src[(size_t)t * E + e];
  }
}

// full mean aggregation (layer 1): out[t][n][d] = mean over in-edges of X[t][src][d]
__global__ void k_agg(const float* __restrict__ X, const int* __restrict__ rowptr,
                      const int* __restrict__ csr, float* __restrict__ out, int dim) {
  int n = blockIdx.x, t = blockIdx.y, d = threadIdx.x;
  int beg = rowptr[t * (NN + 1) + n], end = rowptr[t * (NN + 1) + n + 1];
  const int* es = csr + (size_t)t * E;
  float s = 0.f;
  for (int e = beg; e < end; ++e)
    s += X[((size_t)t * NN + es[e]) * dim + d];
  int degc = end - beg;
  float inv = 1.0f / (float)(degc > 1 ? degc : 1);
  out[((size_t)t * NN + n) * dim + d] = s * inv;
}

// layer-2 inputs at gathered nodes only: selfg = h1[idx], agg2g = mean_agg(h1)[idx]
// grid (P, tch), block H. idx pre-offset to chunk start.
__global__ __launch_bounds__(256) void k_gather2(
    const float* __restrict__ h1, const int* __restrict__ idx,
    const int* __restrict__ rowptr, const int* __restrict__ csr,
    float* __restrict__ selfg, float* __restrict__ agg2g) {
  int p = blockIdx.x, tl = blockIdx.y, d = threadIdx.x;
  int node = idx[(size_t)tl * P + p];
  size_t orow = ((size_t)tl * P + p) * H;
  selfg[orow + d] = h1[((size_t)tl * NN + node) * H + d];
  int beg = rowptr[tl * (NN + 1) + node], end = rowptr[tl * (NN + 1) + node + 1];
  const int* es = csr + (size_t)tl * E;
  float s = 0.f;
  for (int e = beg; e < end; ++e)
    s += h1[((size_t)tl * NN + es[e]) * H + d];
  int degc = end - beg;
  float inv = 1.0f / (float)(degc > 1 ? degc : 1);
  agg2g[orow + d] = s * inv;
}

// L2-normalize h2g rows (H) and write to att_out[(t0+tl)*P+p][colofs+d]
__global__ __launch_bounds__(256) void k_norm_write(
    const float* __restrict__ h2g, float* __restrict__ att_out, int t0, int colofs) {
  int p = blockIdx.x, tl = blockIdx.y, d = threadIdx.x;
  float v = h2g[((size_t)tl * P + p) * H + d];
  float ss = v * v;
  for (int off = 32; off; off >>= 1) ss += __shfl_xor(ss, off);
  __shared__ float wsum[4];
  int lane = d & 63, wid = d >> 6;
  if (lane == 0) wsum[wid] = ss;
  __syncthreads();
  float tot = wsum[0] + wsum[1] + wsum[2] + wsum[3];
  float scale = 1.0f / fmaxf(sqrtf(tot), 1e-12f);
  att_out[((size_t)(t0 + tl) * P + p) * D + colofs + d] = v * scale;
}

// ---------------------------------------------------------------------------
// Generic fp32 GEMM: C[M,N] = op(A[M,K] @ B[K,N] + bias + Cin)
// 64x64 tile, 256 threads, 4x4 microtile, BK=16. M,N multiples of 64; K of 16.
__global__ __launch_bounds__(256) void k_gemm(
    const float* __restrict__ A, const float* __restrict__ B,
    const float* __restrict__ bias, const float* __restrict__ Cin,
    float* __restrict__ C, int M, int N, int K, int relu) {
  __shared__ float As[16][65];
  __shared__ float Bs[16][64];
  const int tid = threadIdx.x;
  const int row0 = blockIdx.y * 64;
  const int col0 = blockIdx.x * 64;
  const int tx = tid & 15, ty = tid >> 4;
  const int ar = tid >> 2;
  const int ac = (tid & 3) << 2;
  const int br = tid >> 4;
  const int bc = (tid & 15) << 2;

  float acc[4][4] = {};
  for (int k0 = 0; k0 < K; k0 += 16) {
    float4 a4 = *(const float4*)(A + (size_t)(row0 + ar) * K + k0 + ac);
    As[ac + 0][ar] = a4.x; As[ac + 1][ar] = a4.y;
    As[ac + 2][ar] = a4.z; As[ac + 3][ar] = a4.w;
    *(float4*)&Bs[br][bc] = *(const float4*)(B + (size_t)(k0 + br) * N + col0 + bc);
    __syncthreads();
#pragma unroll
    for (int kk = 0; kk < 16; ++kk) {
      float a0 = As[kk][ty * 4 + 0], a1 = As[kk][ty * 4 + 1];
      float a2 = As[kk][ty * 4 + 2], a3 = As[kk][ty * 4 + 3];
      float b0 = Bs[kk][tx * 4 + 0], b1 = Bs[kk][tx * 4 + 1];
      float b2 = Bs[kk][tx * 4 + 2], b3 = Bs[kk][tx * 4 + 3];
      acc[0][0] += a0 * b0; acc[0][1] += a0 * b1; acc[0][2] += a0 * b2; acc[0][3] += a0 * b3;
      acc[1][0] += a1 * b0; acc[1][1] += a1 * b1; acc[1][2] += a1 * b2; acc[1][3] += a1 * b3;
      acc[2][0] += a2 * b0; acc[2][1] += a2 * b1; acc[2][2] += a2 * b2; acc[2][3] += a2 * b3;
      acc[3][0] += a3 * b0; acc[3][1] += a3 * b1; acc[3][2] += a3 * b2; acc[3][3] += a3 * b3;
    }
    __syncthreads();
  }
  float bv0 = 0, bv1 = 0, bv2 = 0, bv3 = 0;
  if (bias) {
    bv0 = bias[col0 + tx * 4 + 0]; bv1 = bias[col0 + tx * 4 + 1];
    bv2 = bias[col0 + tx * 4 + 2]; bv3 = bias[col0 + tx * 4 + 3];
  }
#pragma unroll
  for (int i = 0; i < 4; ++i) {
    size_t cofs = (size_t)(row0 + ty * 4 + i) * N + col0 + tx * 4;
    float4 r;
    r.x = acc[i][0] + bv0; r.y = acc[i][1] + bv1;
    r.z = acc[i][2] + bv2; r.w = acc[i][3] + bv3;
    if (Cin) {
      float4 c = *(const float4*)(Cin + cofs);
      r.x += c.x; r.y += c.y; r.z += c.z; r.w += c.w;
    }
    if (relu) {
      r.x = fmaxf(r.x, 0.f); r.y = fmaxf(r.y, 0.f);
      r.z = fmaxf(r.z, 0.f); r.w = fmaxf(r.w, 0.f);
    }
    *(float4*)(C + cofs) = r;
  }
}

static inline void gemm(hipStream_t st, const float* A, const float* B,
                        const float* bias, const float* Cin, float* C,
                        int M, int N, int K, int relu) {
  dim3 g(N / 64, M / 64), b(256);
  k_gemm<<<g, b, 0, st>>>(A, B, bias, Cin, C, M, N, K, relu);
}

// ---------------------------------------------------------------------------
// transpose-in: hc[p-major] <- att[t-major], chunk starting at p0
// grid (PC, T), block 128 (one float4 per thread over D=512)
__global__ __launch_bounds__(128) void k_tin(
    const float* __restrict__ att, float* __restrict__ hc, int p0) {
  int p = blockIdx.x, t = blockIdx.y, d4 = threadIdx.x * 4;
  *(float4*)(hc + ((size_t)p * T + t) * D + d4) =
      *(const float4*)(att + ((size_t)t * P + p0 + p) * D + d4);
}

// windowed attention, p-major. one wave per (p,head); writes o in-place over q.
__global__ __launch_bounds__(256) void k_attn(
    const float* __restrict__ kx, const float* __restrict__ vx, float* __restrict__ q) {
  int p = blockIdx.x >> 1;
  int hh = ((blockIdx.x & 1) << 2) + (threadIdx.x >> 6);
  int d = threadIdx.x & 63;
  size_t base = (size_t)p * T * D + hh * HD + d;
  float qr[16], kr[16], vr[16];
#pragma unroll
  for (int t = 0; t < 16; ++t) {
    qr[t] = q[base + t * D]; kr[t] = kx[base + t * D]; vr[t] = vx[base + t * D];
  }
  const float scale = 0.125f;  // 1/sqrt(64)
#pragma unroll
  for (int t = 0; t < 16; ++t) {
    float sc[4];
#pragma unroll
    for (int j = 0; j < 4; ++j) {
      int s = t - 3 + j;
      int sci = s < 0 ? 0 : s;
      float ps = qr[t] * kr[sci];
      for (int off = 32; off; off >>= 1) ps += __shfl_xor(ps, off);
      sc[j] = (s >= 0) ? ps * scale : -1e30f;
    }
    float m = fmaxf(fmaxf(sc[0], sc[1]), fmaxf(sc[2], sc[3]));
    float sum = 0.f, od = 0.f;
#pragma unroll
    for (int j = 0; j < 4; ++j) {
      int s = t - 3 + j;
      int sci = s < 0 ? 0 : s;
      float e = expf(sc[j] - m);
      sum += e;
      od += e * vr[sci];
    }
    q[base + t * D] = od / sum;
  }
}

// LayerNorm over D=512; grid = rows, block 256.
__global__ __launch_bounds__(256) void k_ln(
    const float* __restrict__ x, float* __restrict__ out,
    const float* __restrict__ g, const float* __restrict__ b) {
  size_t r = blockIdx.x;
  int d = threadIdx.x;
  float x0 = x[r * D + d], x1 = x[r * D + 256 + d];
  float s = x0 + x1, ss = x0 * x0 + x1 * x1;
  for (int off = 32; off; off >>= 1) { s += __shfl_xor(s, off); ss += __shfl_xor(ss, off); }
  __shared__ float as[4], as2[4];
  int lane = d & 63, wid = d >> 6;
  if (lane == 0) { as[wid] = s; as2[wid] = ss; }
  __syncthreads();
  s = as[0] + as[1] + as[2] + as[3];
  ss = as2[0] + as2[1] + as2[2] + as2[3];
  float mean = s * (1.0f / 512.0f);
  float var = ss * (1.0f / 512.0f) - mean * mean;
  float rstd = rsqrtf(var + 1e-5f);
  out[r * D + d]       = (x0 - mean) * rstd * g[d] + b[d];
  out[r * D + 256 + d] = (x1 - mean) * rstd * g[d + 256] + b[d + 256];
}

// final projection from p-major chunk: out_y[t*P + p0 + p] = dot(hc row, w)
__global__ __launch_bounds__(256) void k_out(
    const float* __restrict__ hc, const float* __restrict__ w,
    float* __restrict__ out_y, int p0) {
  int r = blockIdx.x * 4 + (threadIdx.x >> 6);  // r = p_local*T + t
  int lane = threadIdx.x & 63;
  float s = 0.f;
#pragma unroll
  for (int i = 0; i < 8; ++i)
    s += hc[(size_t)r * D + lane + i * 64] * w[lane + i * 64];
  for (int off = 32; off; off >>= 1) s += __shfl_xor(s, off);
  if (lane == 0) {
    int pl = r >> 4, t = r & 15;
    out_y[(size_t)t * P + p0 + pl] = s;
  }
}

// ---------------------------------------------------------------------------
extern "C" void kernel_launch(void* const* d_in, const int* in_sizes, int n_in,
                              void* d_out, int out_size, void* d_ws, size_t ws_size,
                              hipStream_t stream) {
  const float* x_i  = (const float*)d_in[0];
  const float* x_j  = (const float*)d_in[1];
  const int* src_i  = (const int*)d_in[2];
  const int* dst_i  = (const int*)d_in[3];
  const int* src_j  = (const int*)d_in[4];
  const int* dst_j  = (const int*)d_in[5];
  const int* idx_i  = (const int*)d_in[6];
  const int* idx_j  = (const int*)d_in[7];
  const float* W1s  = (const float*)d_in[8];
  const float* W1n  = (const float*)d_in[9];
  const float* b1   = (const float*)d_in[10];
  const float* W2s  = (const float*)d_in[11];
  const float* W2n  = (const float*)d_in[12];
  const float* b2   = (const float*)d_in[13];
  const float* Wq   = (const float*)d_in[14];
  const float* Wk   = (const float*)d_in[15];
  const float* Wv   = (const float*)d_in[16];
  const float* bq   = (const float*)d_in[17];
  const float* bk   = (const float*)d_in[18];
  const float* bv   = (const float*)d_in[19];
  const float* Wo   = (const float*)d_in[20];
  const float* bo   = (const float*)d_in[21];
  const float* Wf1  = (const float*)d_in[22];
  const float* bf1  = (const float*)d_in[23];
  const float* Wf2  = (const float*)d_in[24];
  const float* bf2  = (const float*)d_in[25];
  const float* g1   = (const float*)d_in[26];
  const float* bg1  = (const float*)d_in[27];
  const float* g2   = (const float*)d_in[28];
  const float* bg2  = (const float*)d_in[29];
  const float* Wout = (const float*)d_in[30];

  float* out_att = (float*)d_out;                       // [T,P,D]
  float* out_y   = out_att + (size_t)T * P * D;         // [T,P]

  // ---- adaptive chunk sizes from ws_size (deterministic across calls) ----
  const size_t cap = ws_size / 4;  // capacity in 4-byte units
  auto s1need = [](size_t c) {
    return c * ((size_t)NN * H + (size_t)NN * DIN + 3 * (size_t)P * H +
                NN + (NN + 1) + E);
  };
  int TCH = 2;
  for (int c = 8; c >= 2; c >>= 1) if (s1need(c) <= cap) { TCH = c; break; }
  int PC = 128;
  for (int c = 4096; c >= 128; c >>= 1)
    if ((size_t)5 * c * T * D <= cap) { PC = c; break; }

  // ---- Stage 1: GraphSAGE for both graphs ----
  {
    float* h1    = (float*)d_ws;                        // [TCH*NN, H]
    float* agg1  = h1 + (size_t)TCH * NN * H;           // [TCH*NN, DIN]
    float* selfg = agg1 + (size_t)TCH * NN * DIN;       // [TCH*P, H]
    float* agg2g = selfg + (size_t)TCH * P * H;         // [TCH*P, H]
    float* h2g   = agg2g + (size_t)TCH * P * H;         // [TCH*P, H]
    int* counts  = (int*)(h2g + (size_t)TCH * P * H);   // [TCH*NN]
    int* rowptr  = counts + (size_t)TCH * NN;           // [TCH*(NN+1)]
    int* csr     = rowptr + (size_t)TCH * (NN + 1);     // [TCH*E]
    const int MCH = TCH * NN;

    for (int gi = 0; gi < 2; ++gi) {
      const float* xg = gi ? x_j : x_i;
      const int* srcg = gi ? src_j : src_i;
      const int* dstg = gi ? dst_j : dst_i;
      const int* idxg = gi ? idx_j : idx_i;
      int colofs = gi * H;
      for (int t0 = 0; t0 < T; t0 += TCH) {
        const float* xc = xg + (size_t)t0 * NN * DIN;
        const int* srcc = srcg + (size_t)t0 * E;
        const int* dstc = dstg + (size_t)t0 * E;
        dim3 eg((E + 255) / 256, TCH);
        hipMemsetAsync(counts, 0, sizeof(int) * TCH * NN, stream);
        k_count<<<eg, 256, 0, stream>>>(dstc, counts);
        k_scan<<<TCH, 1024, 0, stream>>>(counts, rowptr);
        hipMemsetAsync(counts, 0, sizeof(int) * TCH * NN, stream);
        k_scatter<<<eg, 256, 0, stream>>>(srcc, dstc, rowptr, counts, csr);
        // layer 1: h1 = relu(x@W1s + mean_agg(x)@W1n + b1)
        k_agg<<<dim3(NN, TCH), DIN, 0, stream>>>(xc, rowptr, csr, agg1, DIN);
        gemm(stream, xc,   W1s, b1, nullptr, h1, MCH, H, DIN, 0);
        gemm(stream, agg1, W1n, nullptr, h1, h1, MCH, H, DIN, 1);
        // layer 2 only at gathered nodes
        k_gather2<<<dim3(P, TCH), H, 0, stream>>>(h1, idxg + (size_t)t0 * P,
                                                  rowptr, csr, selfg, agg2g);
        gemm(stream, selfg, W2s, b2, nullptr, h2g, TCH * P, H, H, 0);
        gemm(stream, agg2g, W2n, nullptr, h2g, h2g, TCH * P, H, H, 0);
        k_norm_write<<<dim3(P, TCH), H, 0, stream>>>(h2g, out_att, t0, colofs);
      }
    }
  }

  // ---- Stage 2: transformer, p-major chunks ----
  {
    const size_t chunkf = (size_t)PC * T * D;
    float* hc = (float*)d_ws;
    float* qc = hc + chunkf;
    float* kc = qc + chunkf;
    float* vc = kc + chunkf;
    float* tc = vc + chunkf;
    float* ffb = kc;                 // FF buffer aliases k (free after attn)
    const int R2 = T * PC;           // rows per chunk
    const int FSUB = R2 / 4;         // FSUB*FF == R2*D == chunkf exactly

    for (int p0 = 0; p0 < P; p0 += PC) {
      k_tin<<<dim3(PC, T), 128, 0, stream>>>(out_att, hc, p0);
      for (int l = 0; l < LAY; ++l) {
        gemm(stream, hc, Wq + (size_t)l * D * D, bq + l * D, nullptr, qc, R2, D, D, 0);
        gemm(stream, hc, Wk + (size_t)l * D * D, bk + l * D, nullptr, kc, R2, D, D, 0);
        gemm(stream, hc, Wv + (size_t)l * D * D, bv + l * D, nullptr, vc, R2, D, D, 0);
        k_attn<<<PC * 2, 256, 0, stream>>>(kc, vc, qc);  // o -> qc in-place
        gemm(stream, qc, Wo + (size_t)l * D * D, bo + l * D, hc, tc, R2, D, D, 0);
        k_ln<<<R2, 256, 0, stream>>>(tc, hc, g1 + l * D, bg1 + l * D);
        for (int m0 = 0; m0 < R2; m0 += FSUB) {
          gemm(stream, hc + (size_t)m0 * D, Wf1 + (size_t)l * D * FF, bf1 + l * FF,
               nullptr, ffb, FSUB, FF, D, 1);
          gemm(stream, ffb, Wf2 + (size_t)l * FF * D, bf2 + l * D,
               hc + (size_t)m0 * D, tc + (size_t)m0 * D, FSUB, D, FF, 0);
        }
        k_ln<<<R2, 256, 0, stream>>>(tc, hc, g2 + l * D, bg2 + l * D);
      }
      k_out<<<R2 / 4, 256, 0, stream>>>(hc, Wout, out_y, p0);
    }
  }
}

// Round 3
// 6201.402 us; speedup vs baseline: 3.0757x; 3.0757x over previous
//
#include <hip/hip_runtime.h>
#include <hip/hip_bf16.h>
#include <math.h>

typedef __hip_bfloat16 bf16;
typedef __attribute__((ext_vector_type(8))) short bf16x8;
typedef __attribute__((ext_vector_type(4))) float f32x4;

// Problem constants
constexpr int T    = 16;
constexpr int NN   = 20000;
constexpr int E    = 320000;
constexpr int P    = 4096;
constexpr int DIN  = 128;
constexpr int H    = 256;
constexpr int NH   = 8;
constexpr int LAY  = 2;
constexpr int FF   = 2048;
constexpr int D    = 2 * H;       // 512
constexpr int HD   = D / NH;      // 64

// ---------------------------------------------------------------------------
// CSR build
__global__ void k_count(const int* __restrict__ dst, int* __restrict__ counts) {
  int e = blockIdx.x * 256 + threadIdx.x;
  int t = blockIdx.y;
  if (e < E) atomicAdd(&counts[t * NN + dst[(size_t)t * E + e]], 1);
}

__global__ __launch_bounds__(1024) void k_scan(const int* __restrict__ counts,
                                               int* __restrict__ rowptr) {
  __shared__ int s[1024];
  int t = blockIdx.x, tid = threadIdx.x;
  int running = 0;
  for (int base = 0; base < NN; base += 1024) {
    int i = base + tid;
    int v = (i < NN) ? counts[t * NN + i] : 0;
    s[tid] = v;
    __syncthreads();
    for (int off = 1; off < 1024; off <<= 1) {
      int u = (tid >= off) ? s[tid - off] : 0;
      __syncthreads();
      s[tid] += u;
      __syncthreads();
    }
    if (i < NN) rowptr[t * (NN + 1) + i] = running + s[tid] - v;
    int tot = s[1023];
    __syncthreads();
    running += tot;
  }
  if (tid == 0) rowptr[t * (NN + 1) + NN] = running;
}

__global__ void k_scatter(const int* __restrict__ src, const int* __restrict__ dst,
                          const int* __restrict__ rowptr, int* __restrict__ cur,
                          int* __restrict__ csr) {
  int e = blockIdx.x * 256 + threadIdx.x;
  int t = blockIdx.y;
  if (e < E) {
    int dd = dst[(size_t)t * E + e];
    int pos = rowptr[t * (NN + 1) + dd] + atomicAdd(&cur[t * NN + dd], 1);
    csr[(size_t)t * E + pos] = src[(size_t)t * E + e];
  }
}

// convert x chunk fp32 -> xcat cols 0..127 (bf16, row stride 256)
__global__ __launch_bounds__(128) void k_cx(const float* __restrict__ x,
                                            bf16* __restrict__ xcat) {
  int n = blockIdx.x, tl = blockIdx.y, d = threadIdx.x;
  size_t row = (size_t)tl * NN + n;
  xcat[row * 256 + d] = __float2bfloat16(x[row * 128 + d]);
}

// layer-1 mean agg: reads xcat cols 0..127, writes cols 128..255
__global__ __launch_bounds__(128) void k_agg1(bf16* __restrict__ xcat,
    const int* __restrict__ rowptr, const int* __restrict__ csr) {
  int n = blockIdx.x, tl = blockIdx.y, d = threadIdx.x;
  int beg = rowptr[tl * (NN + 1) + n], end = rowptr[tl * (NN + 1) + n + 1];
  const int* es = csr + (size_t)tl * E;
  float s = 0.f;
  for (int e = beg; e < end; ++e)
    s += __bfloat162float(xcat[((size_t)tl * NN + es[e]) * 256 + d]);
  int degc = end - beg;
  float inv = 1.0f / (float)(degc > 1 ? degc : 1);
  xcat[((size_t)tl * NN + n) * 256 + 128 + d] = __float2bfloat16(s * inv);
}

// layer-2 inputs at gathered nodes: cat2 = [h1[idx] | mean_agg(h1)[idx]]
__global__ __launch_bounds__(256) void k_g2(const bf16* __restrict__ h1,
    const int* __restrict__ idx, const int* __restrict__ rowptr,
    const int* __restrict__ csr, bf16* __restrict__ cat2) {
  int p = blockIdx.x, tl = blockIdx.y, d = threadIdx.x;
  int node = idx[(size_t)tl * P + p];
  size_t orow = ((size_t)tl * P + p) * 512;
  cat2[orow + d] = h1[((size_t)tl * NN + node) * 256 + d];
  int beg = rowptr[tl * (NN + 1) + node], end = rowptr[tl * (NN + 1) + node + 1];
  const int* es = csr + (size_t)tl * E;
  float s = 0.f;
  for (int e = beg; e < end; ++e)
    s += __bfloat162float(h1[((size_t)tl * NN + es[e]) * 256 + d]);
  int degc = end - beg;
  float inv = 1.0f / (float)(degc > 1 ? degc : 1);
  cat2[orow + 256 + d] = __float2bfloat16(s * inv);
}

// L2-normalize h2g rows (fp32), write att_out fp32 (t-major) + hb bf16 (p-major)
__global__ __launch_bounds__(256) void k_nw(const float* __restrict__ h2g,
    float* __restrict__ att, bf16* __restrict__ hb, int t0, int colofs) {
  int p = blockIdx.x, tl = blockIdx.y, d = threadIdx.x;
  float v = h2g[((size_t)tl * P + p) * 256 + d];
  float ss = v * v;
  for (int off = 32; off; off >>= 1) ss += __shfl_xor(ss, off);
  __shared__ float wsum[4];
  int lane = d & 63, wid = d >> 6;
  if (lane == 0) wsum[wid] = ss;
  __syncthreads();
  float tot = wsum[0] + wsum[1] + wsum[2] + wsum[3];
  float scale = 1.0f / fmaxf(sqrtf(tot), 1e-12f);
  float o = v * scale;
  int t = t0 + tl;
  att[((size_t)t * P + p) * 512 + colofs + d] = o;
  hb[((size_t)p * T + t) * 512 + colofs + d] = __float2bfloat16(o);
}

// ---------------------------------------------------------------------------
// bf16 MFMA GEMM (m97 structure): C[M,N] = op(A[M,K] @ Bt[N,K]^T + bias + Cin)
// 128x128 tile, BK=32, 256 threads = 4 waves (2x2), each wave 4x4 16x16x32 MFMAs.
// A row-major bf16, Bt row-major bf16 [N][K]. M any (clamped), N%128==0, K%32==0.
__global__ __launch_bounds__(256) void k_mm(
    const bf16* __restrict__ A, const bf16* __restrict__ Bt,
    const float* __restrict__ bias, const bf16* __restrict__ Cin,
    void* __restrict__ Cout, int M, int N, int K, int relu, int obf) {
  __shared__ __align__(16) bf16 As[128 * 32];
  __shared__ __align__(16) bf16 Bs[128 * 32];
  const int tid = threadIdx.x;
  const int w = tid >> 6, lane = tid & 63;
  const int row0 = blockIdx.y * 128, col0 = blockIdx.x * 128;
  const int wm = (w >> 1) * 64, wn = (w & 1) * 64;
  const int lr = lane >> 4, lc = lane & 15;   // quad, col-in-frag
  const int sr = lane >> 2;                   // staging row-in-segment (0..15)
  const int sc = (lane & 3) * 8;              // staging col (0,8,16,24)

  f32x4 acc[4][4] = {};

  for (int k0 = 0; k0 < K; k0 += 32) {
    // stage A and Bt tiles: each wave covers segments w and w+4 (16 rows each)
    for (int s = w; s < 8; s += 4) {
      int gr = row0 + s * 16 + sr; if (gr >= M) gr = M - 1;
      const bf16* ga = A + (size_t)gr * K + k0 + sc;
      __builtin_amdgcn_global_load_lds(
          (const __attribute__((address_space(1))) void*)ga,
          (__attribute__((address_space(3))) void*)(As + s * 16 * 32), 16, 0, 0);
      int gn = col0 + s * 16 + sr;
      const bf16* gb = Bt + (size_t)gn * K + k0 + sc;
      __builtin_amdgcn_global_load_lds(
          (const __attribute__((address_space(1))) void*)gb,
          (__attribute__((address_space(3))) void*)(Bs + s * 16 * 32), 16, 0, 0);
    }
    __syncthreads();
    bf16x8 af[4], bfr[4];
#pragma unroll
    for (int i = 0; i < 4; ++i)
      af[i] = *(const bf16x8*)(As + (wm + i * 16 + lc) * 32 + lr * 8);
#pragma unroll
    for (int j = 0; j < 4; ++j)
      bfr[j] = *(const bf16x8*)(Bs + (wn + j * 16 + lc) * 32 + lr * 8);
#pragma unroll
    for (int i = 0; i < 4; ++i)
#pragma unroll
      for (int j = 0; j < 4; ++j)
        acc[i][j] = __builtin_amdgcn_mfma_f32_16x16x32_bf16(af[i], bfr[j], acc[i][j], 0, 0, 0);
    __syncthreads();
  }

  // epilogue: C/D layout col=lane&15, row=(lane>>4)*4+reg  [m89/m91]
#pragma unroll
  for (int i = 0; i < 4; ++i) {
    int gm0 = row0 + wm + i * 16 + lr * 4;
#pragma unroll
    for (int j = 0; j < 4; ++j) {
      int gn = col0 + wn + j * 16 + lc;
      float bb = bias ? bias[gn] : 0.f;
#pragma unroll
      for (int r = 0; r < 4; ++r) {
        int gm = gm0 + r;
        if (gm < M) {
          float v = acc[i][j][r] + bb;
          if (Cin) v += __bfloat162float(Cin[(size_t)gm * N + gn]);
          if (relu) v = fmaxf(v, 0.f);
          if (obf) ((bf16*)Cout)[(size_t)gm * N + gn] = __float2bfloat16(v);
          else     ((float*)Cout)[(size_t)gm * N + gn] = v;
        }
      }
    }
  }
}

static inline void mm(hipStream_t st, const bf16* A, const bf16* Bt,
                      const float* bias, const bf16* Cin, void* C,
                      int M, int N, int K, int relu, int obf) {
  dim3 g(N / 128, (M + 127) / 128);
  k_mm<<<g, 256, 0, st>>>(A, Bt, bias, Cin, C, M, N, K, relu, obf);
}

// ---------------------------------------------------------------------------
// transpose-convert weight: dst[n*ldst + koff + k] = bf16(src[k*Ns + n])
__global__ void k_wt(const float* __restrict__ src, bf16* __restrict__ dst,
                     int Ks, int Ns, int ldst, int koff) {
  int n = blockIdx.x * 16 + threadIdx.x;
  int k = blockIdx.y * 16 + threadIdx.y;
  if (n < Ns && k < Ks)
    dst[(size_t)n * ldst + koff + k] = __float2bfloat16(src[(size_t)k * Ns + n]);
}

// concat qkv biases: qkvb[l*1536 + j]
__global__ void k_cb(const float* __restrict__ bq, const float* __restrict__ bk,
                     const float* __restrict__ bv, float* __restrict__ qkvb) {
  int i = blockIdx.x * 256 + threadIdx.x;
  if (i < 2 * 1536) {
    int l = i / 1536, j = i % 1536;
    float v = (j < 512) ? bq[l * 512 + j]
            : (j < 1024) ? bk[l * 512 + j - 512] : bv[l * 512 + j - 1024];
    qkvb[i] = v;
  }
}

// ---------------------------------------------------------------------------
// windowed attention: qkv bf16 [R2][1536] (chunk-local p-major), o -> oc [R2][512]
__global__ __launch_bounds__(256) void k_attn(const bf16* __restrict__ qkv,
                                              bf16* __restrict__ oc) {
  int p = blockIdx.x >> 1;
  int hh = ((blockIdx.x & 1) << 2) + (threadIdx.x >> 6);
  int d = threadIdx.x & 63;
  size_t rb = (size_t)p * T * 1536 + hh * 64 + d;
  float qr[16], kr[16], vr[16];
#pragma unroll
  for (int t = 0; t < 16; ++t) {
    qr[t] = __bfloat162float(qkv[rb + t * 1536]);
    kr[t] = __bfloat162float(qkv[rb + t * 1536 + 512]);
    vr[t] = __bfloat162float(qkv[rb + t * 1536 + 1024]);
  }
  const float scale = 0.125f;
#pragma unroll
  for (int t = 0; t < 16; ++t) {
    float sc4[4];
#pragma unroll
    for (int j = 0; j < 4; ++j) {
      int s = t - 3 + j;
      int sci = s < 0 ? 0 : s;
      float ps = qr[t] * kr[sci];
      for (int off = 32; off; off >>= 1) ps += __shfl_xor(ps, off);
      sc4[j] = (s >= 0) ? ps * scale : -1e30f;
    }
    float m = fmaxf(fmaxf(sc4[0], sc4[1]), fmaxf(sc4[2], sc4[3]));
    float sum = 0.f, od = 0.f;
#pragma unroll
    for (int j = 0; j < 4; ++j) {
      int s = t - 3 + j;
      int sci = s < 0 ? 0 : s;
      float e = expf(sc4[j] - m);
      sum += e;
      od += e * vr[sci];
    }
    oc[((size_t)p * T + t) * 512 + hh * 64 + d] = __float2bfloat16(od / sum);
  }
}

// LayerNorm over D=512: tc fp32 -> hb bf16
__global__ __launch_bounds__(256) void k_ln(const float* __restrict__ x,
    bf16* __restrict__ out, const float* __restrict__ g, const float* __restrict__ b) {
  size_t r = blockIdx.x;
  int d = threadIdx.x;
  float x0 = x[r * 512 + d], x1 = x[r * 512 + 256 + d];
  float s = x0 + x1, ss = x0 * x0 + x1 * x1;
  for (int off = 32; off; off >>= 1) { s += __shfl_xor(s, off); ss += __shfl_xor(ss, off); }
  __shared__ float as[4], as2[4];
  int lane = d & 63, wid = d >> 6;
  if (lane == 0) { as[wid] = s; as2[wid] = ss; }
  __syncthreads();
  s = as[0] + as[1] + as[2] + as[3];
  ss = as2[0] + as2[1] + as2[2] + as2[3];
  float mean = s * (1.0f / 512.0f);
  float var = ss * (1.0f / 512.0f) - mean * mean;
  float rstd = rsqrtf(var + 1e-5f);
  out[r * 512 + d]       = __float2bfloat16((x0 - mean) * rstd * g[d] + b[d]);
  out[r * 512 + 256 + d] = __float2bfloat16((x1 - mean) * rstd * g[d + 256] + b[d + 256]);
}

// final projection: hb bf16 [P*T][512] -> out_y[t*P + p]
__global__ __launch_bounds__(256) void k_out(const bf16* __restrict__ hb,
    const float* __restrict__ w, float* __restrict__ out_y) {
  int r = blockIdx.x * 4 + (threadIdx.x >> 6);
  int lane = threadIdx.x & 63;
  float s = 0.f;
#pragma unroll
  for (int i = 0; i < 8; ++i)
    s += __bfloat162float(hb[(size_t)r * 512 + lane + i * 64]) * w[lane + i * 64];
  for (int off = 32; off; off >>= 1) s += __shfl_xor(s, off);
  if (lane == 0) out_y[(size_t)(r & 15) * P + (r >> 4)] = s;
}

// ---------------------------------------------------------------------------
extern "C" void kernel_launch(void* const* d_in, const int* in_sizes, int n_in,
                              void* d_out, int out_size, void* d_ws, size_t ws_size,
                              hipStream_t stream) {
  const float* x_i  = (const float*)d_in[0];
  const float* x_j  = (const float*)d_in[1];
  const int* src_i  = (const int*)d_in[2];
  const int* dst_i  = (const int*)d_in[3];
  const int* src_j  = (const int*)d_in[4];
  const int* dst_j  = (const int*)d_in[5];
  const int* idx_i  = (const int*)d_in[6];
  const int* idx_j  = (const int*)d_in[7];
  const float* W1s  = (const float*)d_in[8];
  const float* W1n  = (const float*)d_in[9];
  const float* b1   = (const float*)d_in[10];
  const float* W2s  = (const float*)d_in[11];
  const float* W2n  = (const float*)d_in[12];
  const float* b2   = (const float*)d_in[13];
  const float* Wq   = (const float*)d_in[14];
  const float* Wk   = (const float*)d_in[15];
  const float* Wv   = (const float*)d_in[16];
  const float* bq   = (const float*)d_in[17];
  const float* bk   = (const float*)d_in[18];
  const float* bv   = (const float*)d_in[19];
  const float* Wo   = (const float*)d_in[20];
  const float* bo   = (const float*)d_in[21];
  const float* Wf1  = (const float*)d_in[22];
  const float* bf1  = (const float*)d_in[23];
  const float* Wf2  = (const float*)d_in[24];
  const float* bf2  = (const float*)d_in[25];
  const float* g1   = (const float*)d_in[26];
  const float* bg1  = (const float*)d_in[27];
  const float* g2   = (const float*)d_in[28];
  const float* bg2  = (const float*)d_in[29];
  const float* Wout = (const float*)d_in[30];

  float* out_att = (float*)d_out;
  float* out_y   = out_att + (size_t)T * P * D;

  // ---- persistent workspace regions ----
  char* w8 = (char*)d_ws;
  auto alloc = [&](size_t bytes) {
    char* p = w8; w8 += (bytes + 255) & ~(size_t)255; return p;
  };
  bf16* W1t   = (bf16*)alloc((size_t)256 * 256 * 2);
  bf16* W2t   = (bf16*)alloc((size_t)256 * 512 * 2);
  bf16* Wqkvt = (bf16*)alloc((size_t)2 * 1536 * 512 * 2);
  bf16* Wot   = (bf16*)alloc((size_t)2 * 512 * 512 * 2);
  bf16* Wf1t  = (bf16*)alloc((size_t)2 * 2048 * 512 * 2);
  bf16* Wf2t  = (bf16*)alloc((size_t)2 * 512 * 2048 * 2);
  float* qkvb = (float*)alloc((size_t)2 * 1536 * 4);
  bf16* hb    = (bf16*)alloc((size_t)P * T * D * 2);
  char* scratch = w8;
  size_t scrcap = ws_size - (size_t)(w8 - (char*)d_ws);

  // ---- chunk sizing ----
  auto s1bytes = [](size_t c) {
    return c * ((size_t)NN * 256 * 2 * 2 + (size_t)P * 512 * 2 +
                (size_t)P * 256 * 4 + (size_t)(NN + NN + 1 + E) * 4) + 4096;
  };
  int TCH = 1;
  for (int c = 8; c >= 1; c >>= 1) if (s1bytes(c) <= scrcap) { TCH = c; break; }
  int PC = 128;
  for (int c = 4096; c >= 128; c >>= 1)
    if ((size_t)c * 114688 + 4096 <= scrcap) { PC = c; break; }

  // ---- weight conversion (per launch; ~13 MB) ----
  {
    dim3 bw(16, 16);
    k_wt<<<dim3(16, 8),  bw, 0, stream>>>(W1s, W1t, 128, 256, 256, 0);
    k_wt<<<dim3(16, 8),  bw, 0, stream>>>(W1n, W1t, 128, 256, 256, 128);
    k_wt<<<dim3(16, 16), bw, 0, stream>>>(W2s, W2t, 256, 256, 512, 0);
    k_wt<<<dim3(16, 16), bw, 0, stream>>>(W2n, W2t, 256, 256, 512, 256);
    for (int l = 0; l < LAY; ++l) {
      const size_t dd = (size_t)512 * 512;
      k_wt<<<dim3(32, 32), bw, 0, stream>>>(Wq + l * dd, Wqkvt + (size_t)l * 1536 * 512,
                                            512, 512, 512, 0);
      k_wt<<<dim3(32, 32), bw, 0, stream>>>(Wk + l * dd, Wqkvt + (size_t)l * 1536 * 512 + dd,
                                            512, 512, 512, 0);
      k_wt<<<dim3(32, 32), bw, 0, stream>>>(Wv + l * dd, Wqkvt + (size_t)l * 1536 * 512 + 2 * dd,
                                            512, 512, 512, 0);
      k_wt<<<dim3(32, 32), bw, 0, stream>>>(Wo + l * dd, Wot + l * dd, 512, 512, 512, 0);
      k_wt<<<dim3(128, 32), bw, 0, stream>>>(Wf1 + (size_t)l * 512 * 2048,
                                             Wf1t + (size_t)l * 2048 * 512, 512, 2048, 512, 0);
      k_wt<<<dim3(32, 128), bw, 0, stream>>>(Wf2 + (size_t)l * 2048 * 512,
                                             Wf2t + (size_t)l * 512 * 2048, 2048, 512, 2048, 0);
    }
    k_cb<<<12, 256, 0, stream>>>(bq, bk, bv, qkvb);
  }

  // ---- Stage 1: GraphSAGE (both graphs), writes att_out + hb ----
  {
    bf16* xcat  = (bf16*)scratch;                       // [TCH*NN][256]
    bf16* h1    = xcat + (size_t)TCH * NN * 256;        // [TCH*NN][256]
    bf16* cat2  = h1 + (size_t)TCH * NN * 256;          // [TCH*P][512]
    float* h2g  = (float*)(cat2 + (size_t)TCH * P * 512);  // [TCH*P][256]
    int* counts = (int*)(h2g + (size_t)TCH * P * 256);
    int* rowptr = counts + (size_t)TCH * NN;
    int* csr    = rowptr + (size_t)TCH * (NN + 1);

    for (int gi = 0; gi < 2; ++gi) {
      const float* xg = gi ? x_j : x_i;
      const int* srcg = gi ? src_j : src_i;
      const int* dstg = gi ? dst_j : dst_i;
      const int* idxg = gi ? idx_j : idx_i;
      for (int t0 = 0; t0 < T; t0 += TCH) {
        const float* xc = xg + (size_t)t0 * NN * DIN;
        const int* srcc = srcg + (size_t)t0 * E;
        const int* dstc = dstg + (size_t)t0 * E;
        dim3 eg((E + 255) / 256, TCH);
        hipMemsetAsync(counts, 0, sizeof(int) * TCH * NN, stream);
        k_count<<<eg, 256, 0, stream>>>(dstc, counts);
        k_scan<<<TCH, 1024, 0, stream>>>(counts, rowptr);
        hipMemsetAsync(counts, 0, sizeof(int) * TCH * NN, stream);
        k_scatter<<<eg, 256, 0, stream>>>(srcc, dstc, rowptr, counts, csr);
        // layer 1: h1 = relu([x|agg] @ [W1s;W1n] + b1)
        k_cx<<<dim3(NN, TCH), 128, 0, stream>>>(xc, xcat);
        k_agg1<<<dim3(NN, TCH), 128, 0, stream>>>(xcat, rowptr, csr);
        mm(stream, xcat, W1t, b1, nullptr, h1, TCH * NN, 256, 256, 1, 1);
        // layer 2 at gathered nodes: h2 = [h1[idx]|agg2[idx]] @ [W2s;W2n] + b2
        k_g2<<<dim3(P, TCH), 256, 0, stream>>>(h1, idxg + (size_t)t0 * P, rowptr, csr, cat2);
        mm(stream, cat2, W2t, b2, nullptr, h2g, TCH * P, 256, 512, 0, 0);
        k_nw<<<dim3(P, TCH), 256, 0, stream>>>(h2g, out_att, hb, t0, gi * 256);
      }
    }
  }

  // ---- Stage 2: transformer on hb (p-major bf16), chunks of PC ----
  {
    bf16* qkvc = (bf16*)scratch;                        // [R2][1536]
    bf16* oc   = qkvc + (size_t)PC * 16 * 1536;         // [R2][512]
    float* tc  = (float*)(oc + (size_t)PC * 16 * 512);  // [R2][512] fp32
    bf16* ffb  = (bf16*)(tc + (size_t)PC * 16 * 512);   // [R2/4][2048]
    const int R2 = PC * T;
    const int FSUB = R2 / 4;

    for (int p0 = 0; p0 < P; p0 += PC) {
      bf16* hbc = hb + (size_t)p0 * T * 512;
      for (int l = 0; l < LAY; ++l) {
        mm(stream, hbc, Wqkvt + (size_t)l * 1536 * 512, qkvb + l * 1536, nullptr,
           qkvc, R2, 1536, 512, 0, 1);
        k_attn<<<PC * 2, 256, 0, stream>>>(qkvc, oc);
        mm(stream, oc, Wot + (size_t)l * 512 * 512, bo + l * 512, hbc, tc, R2, 512, 512, 0, 0);
        k_ln<<<R2, 256, 0, stream>>>(tc, hbc, g1 + l * 512, bg1 + l * 512);
        for (int m0 = 0; m0 < R2; m0 += FSUB) {
          mm(stream, hbc + (size_t)m0 * 512, Wf1t + (size_t)l * 2048 * 512, bf1 + l * 2048,
             nullptr, ffb, FSUB, 2048, 512, 1, 1);
          mm(stream, ffb, Wf2t + (size_t)l * 512 * 2048, bf2 + l * 512,
             hbc + (size_t)m0 * 512, tc + (size_t)m0 * 512, FSUB, 512, 2048, 0, 0);
        }
        k_ln<<<R2, 256, 0, stream>>>(tc, hbc, g2 + l * 512, bg2 + l * 512);
      }
    }
    k_out<<<P * T / 4, 256, 0, stream>>>(hb, Wout, out_y);
  }
}